// Round 1
// baseline (285.448 us; speedup 1.0000x reference)
//
#include <hip/hip_runtime.h>
#include <hip/hip_bf16.h>
#include <math.h>

// Problem constants
#define BATCH 256
#define CIN 3
#define HW 128
#define OC 16
#define POOLED 63          // pooled spatial dim
#define FEAT 63504         // OC*63*63
#define NH 256
#define FANIN 512
#define NO 10
#define CHW (CIN*HW*HW)    // 49152

// ---------------- Kernel 1: transpose inputs (B, CHW) -> (CHW, B) ----------------
__global__ __launch_bounds__(256) void transpose_kernel(const float* __restrict__ in,
                                                        float* __restrict__ out) {
    __shared__ float tile[64][65];
    const int f0 = blockIdx.x * 64;
    const int b0 = blockIdx.y * 64;
    const int t  = threadIdx.x;
    const int tx = t & 63;
    const int ty = t >> 6;          // 0..3
#pragma unroll
    for (int it = 0; it < 16; ++it) {
        int bl = ty + it * 4;       // 0..63
        tile[bl][tx] = in[(size_t)(b0 + bl) * CHW + f0 + tx];
    }
    __syncthreads();
#pragma unroll
    for (int it = 0; it < 16; ++it) {
        int fl = ty + it * 4;       // 0..63
        out[(size_t)(f0 + fl) * BATCH + b0 + tx] = tile[tx][fl];
    }
}

// ---------------- Kernel 2: conv3x3 + bias + relu + maxpool2x2, transposed IO ----
// inT: (C, H, W, B). featsT: (FEAT, B). One block: pooled row i, 3 pooled cols,
// all 16 oc, thread = b.
__global__ __launch_bounds__(256) void conv_pool_kernel(const float* __restrict__ inT,
                                                        const float* __restrict__ cw,
                                                        const float* __restrict__ cb,
                                                        float* __restrict__ featsT) {
    const int b  = threadIdx.x;
    const int i  = blockIdx.y;      // 0..62 pooled row
    const int jt = blockIdx.x;      // 0..20 tile of 3 pooled cols
    const int xbase = 6 * jt;       // input cols xbase..xbase+7
    const int ybase = 2 * i;        // input rows ybase..ybase+3

    float V[CIN][4][8];
    const float* base = inT + b;
#pragma unroll
    for (int c = 0; c < CIN; ++c)
#pragma unroll
        for (int dy = 0; dy < 4; ++dy)
#pragma unroll
            for (int dx = 0; dx < 8; ++dx)
                V[c][dy][dx] =
                    base[(size_t)((c * HW + (ybase + dy)) * HW + (xbase + dx)) * BATCH];

#pragma unroll
    for (int s = 0; s < 3; ++s) {
        const int j = jt * 3 + s;
        for (int oc = 0; oc < OC; ++oc) {
            float a00 = 0.f, a01 = 0.f, a10 = 0.f, a11 = 0.f;
#pragma unroll
            for (int c = 0; c < CIN; ++c)
#pragma unroll
                for (int ky = 0; ky < 3; ++ky)
#pragma unroll
                    for (int kx = 0; kx < 3; ++kx) {
                        const float w = cw[((oc * CIN + c) * 3 + ky) * 3 + kx];
                        a00 += w * V[c][ky    ][2 * s + kx    ];
                        a01 += w * V[c][ky    ][2 * s + kx + 1];
                        a10 += w * V[c][ky + 1][2 * s + kx    ];
                        a11 += w * V[c][ky + 1][2 * s + kx + 1];
                    }
            float m = fmaxf(fmaxf(a00, a01), fmaxf(a10, a11));
            float r = fmaxf(m + cb[oc], 0.0f);
            featsT[(size_t)(oc * 3969 + i * POOLED + j) * BATCH + b] = r;
        }
    }
}

// ---------------- Kernel 3: sparse hidden layer, transposed ----------------------
// hiddenT: (NH, B). Block = one h; 1024 threads = 4 k-splits x 256 b.
__global__ __launch_bounds__(1024) void hidden_kernel(const float* __restrict__ featsT,
                                                      const int* __restrict__ hidx,
                                                      const float* __restrict__ hw,
                                                      const float* __restrict__ hb,
                                                      float* __restrict__ hiddenT) {
    __shared__ float red[1024];
    const int h  = blockIdx.x;
    const int t  = threadIdx.x;
    const int b  = t & 255;
    const int ks = t >> 8;          // 0..3
    const int k0 = ks * 128;
    float acc = 0.f;
    for (int k = k0; k < k0 + 128; ++k) {
        const int idx = hidx[h * FANIN + k];
        acc += featsT[(size_t)idx * BATCH + b] * hw[h * FANIN + k];
    }
    red[t] = acc;
    __syncthreads();
    if (t < 256) {
        float s = red[t] + red[t + 256] + red[t + 512] + red[t + 768] + hb[h];
        hiddenT[h * BATCH + b] = 1.0f / (1.0f + __expf(-s));
    }
}

// ---------------- Kernel 4: dense 256->10 output layer ---------------------------
__global__ __launch_bounds__(256) void out_kernel(const float* __restrict__ hiddenT,
                                                  const float* __restrict__ ow,
                                                  const float* __restrict__ ob,
                                                  float* __restrict__ out) {
    const int o = blockIdx.x;       // 0..9
    const int b = threadIdx.x;      // 0..255
    float acc = 0.f;
    for (int h = 0; h < NH; ++h)
        acc += hiddenT[h * BATCH + b] * ow[o * NH + h];
    out[b * NO + o] = 1.0f / (1.0f + __expf(-(acc + ob[o])));
}

extern "C" void kernel_launch(void* const* d_in, const int* in_sizes, int n_in,
                              void* d_out, int out_size, void* d_ws, size_t ws_size,
                              hipStream_t stream) {
    const float* inputs   = (const float*)d_in[0];
    const float* conv_w   = (const float*)d_in[1];
    const float* conv_b   = (const float*)d_in[2];
    const int*   hidden_i = (const int*)d_in[3];
    const float* hidden_w = (const float*)d_in[4];
    const float* hidden_b = (const float*)d_in[5];
    const float* out_w    = (const float*)d_in[6];
    const float* out_b    = (const float*)d_in[7];
    float* out = (float*)d_out;

    char* ws = (char*)d_ws;
    float* inT     = (float*)ws;                                    // 50,331,648 B
    float* featsT  = (float*)(ws + (size_t)CHW * BATCH * 4);        // 65,028,096 B
    float* hiddenT = (float*)(ws + (size_t)CHW * BATCH * 4
                                 + (size_t)FEAT * BATCH * 4);       //    262,144 B

    transpose_kernel<<<dim3(CHW / 64, BATCH / 64), 256, 0, stream>>>(inputs, inT);
    conv_pool_kernel<<<dim3(21, 63), 256, 0, stream>>>(inT, conv_w, conv_b, featsT);
    hidden_kernel<<<NH, 1024, 0, stream>>>(featsT, hidden_i, hidden_w, hidden_b, hiddenT);
    out_kernel<<<NO, 256, 0, stream>>>(hiddenT, out_w, out_b, out);
}

// Round 2
// 204.708 us; speedup vs baseline: 1.3944x; 1.3944x over previous
//
#include <hip/hip_runtime.h>
#include <hip/hip_bf16.h>
#include <math.h>

// Problem constants
#define BATCH 256
#define CIN 3
#define HW 128
#define OC 16
#define POOLED 63          // pooled spatial dim
#define FEAT 63504         // OC*63*63
#define NH 256
#define FANIN 512
#define NO 10
#define CHW (CIN*HW*HW)    // 49152

// ---------------- Kernel 1: transpose inputs (B, CHW) -> (CHW, B), float4 both sides
__global__ __launch_bounds__(256) void transpose_kernel(const float* __restrict__ in,
                                                        float* __restrict__ out) {
    __shared__ float tile[64][65];   // tile[b_local][f_local]
    const int f0 = blockIdx.x * 64;
    const int b0 = blockIdx.y * 64;
    const int t  = threadIdx.x;
    // read phase: rows = b_local, float4 along f
    {
        const int r  = t >> 4;          // 0..15
        const int cg = t & 15;          // 0..15 (float4 group)
#pragma unroll
        for (int it = 0; it < 4; ++it) {
            const int bl = r + 16 * it; // 0..63
            const float4 v = *(const float4*)&in[(size_t)(b0 + bl) * CHW + f0 + cg * 4];
            tile[bl][cg * 4 + 0] = v.x;
            tile[bl][cg * 4 + 1] = v.y;
            tile[bl][cg * 4 + 2] = v.z;
            tile[bl][cg * 4 + 3] = v.w;
        }
    }
    __syncthreads();
    // write phase: rows = f_local, float4 along b
    {
        const int r = t >> 4;           // 0..15
        const int g = t & 15;           // 0..15 (b float4 group)
#pragma unroll
        for (int it = 0; it < 4; ++it) {
            const int fl = r + 16 * it; // 0..63
            float4 v;
            v.x = tile[g * 4 + 0][fl];
            v.y = tile[g * 4 + 1][fl];
            v.z = tile[g * 4 + 2][fl];
            v.w = tile[g * 4 + 3][fl];
            *(float4*)&out[(size_t)(f0 + fl) * BATCH + b0 + g * 4] = v;
        }
    }
}

// ---------------- Kernel 2: conv3x3 + bias + relu + maxpool2x2, transposed IO ----
// inT: (C, H, W, B). featsT: (FEAT, B). One block: pooled row i, 3 pooled cols,
// all 16 oc, thread = b.  launch_bounds(256,4): VGPR cap 128 so V[96] stays live.
__global__ __launch_bounds__(256, 4) void conv_pool_kernel(const float* __restrict__ inT,
                                                           const float* __restrict__ cw,
                                                           const float* __restrict__ cb,
                                                           float* __restrict__ featsT) {
    const int b  = threadIdx.x;
    const int i  = blockIdx.y;      // 0..62 pooled row
    const int jt = blockIdx.x;      // 0..20 tile of 3 pooled cols
    const int xbase = 6 * jt;       // input cols xbase..xbase+7
    const int ybase = 2 * i;        // input rows ybase..ybase+3

    float V[CIN][4][8];
    const float* base = inT + b;
#pragma unroll
    for (int c = 0; c < CIN; ++c)
#pragma unroll
        for (int dy = 0; dy < 4; ++dy)
#pragma unroll
            for (int dx = 0; dx < 8; ++dx)
                V[c][dy][dx] =
                    base[(size_t)((c * HW + (ybase + dy)) * HW + (xbase + dx)) * BATCH];

    for (int oc = 0; oc < OC; ++oc) {
        const float bias = cb[oc];
#pragma unroll
        for (int s = 0; s < 3; ++s) {
            const int j = jt * 3 + s;
            float a00 = 0.f, a01 = 0.f, a10 = 0.f, a11 = 0.f;
#pragma unroll
            for (int c = 0; c < CIN; ++c)
#pragma unroll
                for (int ky = 0; ky < 3; ++ky)
#pragma unroll
                    for (int kx = 0; kx < 3; ++kx) {
                        const float w = cw[((oc * CIN + c) * 3 + ky) * 3 + kx];
                        a00 += w * V[c][ky    ][2 * s + kx    ];
                        a01 += w * V[c][ky    ][2 * s + kx + 1];
                        a10 += w * V[c][ky + 1][2 * s + kx    ];
                        a11 += w * V[c][ky + 1][2 * s + kx + 1];
                    }
            float m = fmaxf(fmaxf(a00, a01), fmaxf(a10, a11));
            float r = fmaxf(m + bias, 0.0f);
            featsT[(size_t)(oc * 3969 + i * POOLED + j) * BATCH + b] = r;
        }
    }
}

// ---------------- Kernel 3: sparse hidden layer, transposed ----------------------
// hiddenT: (NH, B). Block = one h; 1024 threads = 4 k-splits x 256 b.
// idx/weights staged in LDS so the gather loop pipelines.
__global__ __launch_bounds__(1024, 4) void hidden_kernel(const float* __restrict__ featsT,
                                                         const int* __restrict__ hidx,
                                                         const float* __restrict__ hw,
                                                         const float* __restrict__ hb,
                                                         float* __restrict__ hiddenT) {
    __shared__ int   sidx[FANIN];
    __shared__ float swt[FANIN];
    __shared__ float red[1024];
    const int h  = blockIdx.x;
    const int t  = threadIdx.x;
    if (t < FANIN) {
        sidx[t] = hidx[h * FANIN + t];
        swt[t]  = hw[h * FANIN + t];
    }
    __syncthreads();
    const int b  = t & 255;
    const int ks = t >> 8;          // 0..3
    const int k0 = ks * 128;
    float acc = 0.f;
#pragma unroll 16
    for (int kk = 0; kk < 128; ++kk) {
        const int k = k0 + kk;
        acc += featsT[(size_t)sidx[k] * BATCH + b] * swt[k];
    }
    red[t] = acc;
    __syncthreads();
    if (t < 256) {
        float s = red[t] + red[t + 256] + red[t + 512] + red[t + 768] + hb[h];
        hiddenT[h * BATCH + b] = 1.0f / (1.0f + __expf(-s));
    }
}

// ---------------- Kernel 4: dense 256->10 output layer ---------------------------
__global__ __launch_bounds__(256) void out_kernel(const float* __restrict__ hiddenT,
                                                  const float* __restrict__ ow,
                                                  const float* __restrict__ ob,
                                                  float* __restrict__ out) {
    const int o = blockIdx.x;       // 0..9
    const int b = threadIdx.x;      // 0..255
    float a0 = 0.f, a1 = 0.f, a2 = 0.f, a3 = 0.f;
#pragma unroll 16
    for (int h = 0; h < NH; h += 4) {
        a0 += hiddenT[(h + 0) * BATCH + b] * ow[o * NH + h + 0];
        a1 += hiddenT[(h + 1) * BATCH + b] * ow[o * NH + h + 1];
        a2 += hiddenT[(h + 2) * BATCH + b] * ow[o * NH + h + 2];
        a3 += hiddenT[(h + 3) * BATCH + b] * ow[o * NH + h + 3];
    }
    float acc = (a0 + a1) + (a2 + a3);
    out[b * NO + o] = 1.0f / (1.0f + __expf(-(acc + ob[o])));
}

extern "C" void kernel_launch(void* const* d_in, const int* in_sizes, int n_in,
                              void* d_out, int out_size, void* d_ws, size_t ws_size,
                              hipStream_t stream) {
    const float* inputs   = (const float*)d_in[0];
    const float* conv_w   = (const float*)d_in[1];
    const float* conv_b   = (const float*)d_in[2];
    const int*   hidden_i = (const int*)d_in[3];
    const float* hidden_w = (const float*)d_in[4];
    const float* hidden_b = (const float*)d_in[5];
    const float* out_w    = (const float*)d_in[6];
    const float* out_b    = (const float*)d_in[7];
    float* out = (float*)d_out;

    char* ws = (char*)d_ws;
    float* inT     = (float*)ws;                                    // 50,331,648 B
    float* featsT  = (float*)(ws + (size_t)CHW * BATCH * 4);        // 65,028,096 B
    float* hiddenT = (float*)(ws + (size_t)CHW * BATCH * 4
                                 + (size_t)FEAT * BATCH * 4);       //    262,144 B

    transpose_kernel<<<dim3(CHW / 64, BATCH / 64), 256, 0, stream>>>(inputs, inT);
    conv_pool_kernel<<<dim3(21, 63), 256, 0, stream>>>(inT, conv_w, conv_b, featsT);
    hidden_kernel<<<NH, 1024, 0, stream>>>(featsT, hidden_i, hidden_w, hidden_b, hiddenT);
    out_kernel<<<NO, 256, 0, stream>>>(hiddenT, out_w, out_b, out);
}